// Round 15
// baseline (37.214 us; speedup 1.0000x reference)
//
#include <hip/hip_runtime.h>

// Chamfer distance, B=4, N=M=8192, fp32 in R^3 — MFMA, col-ownership design.
//
// R14 post-mortem: single-kernel regressed (1 block/CU -> barriers stall the
// CU; in-kernel packing 128x redundant). R15 keeps the R12-proven pieces:
// prepack kernel (packs each point once) + barrier-free main streaming
// prepacked rows from global/L2 — but each block now owns 128 cols FULLY
// (all 8192 rows), so the 524K-atomicMin tail, the keys buffer, and the
// separate reduce dispatch all vanish:
//   grid = 2(dir) x 4(b) x 64(xblk) = 512 blocks x 512 thr (2/CU, 16 w/CU).
//   8 waves = 4 row-groups x 2 col-subranges; wave streams 2048 rows (64 jt).
//   Epilogue: xor32 half-combine -> part[4][128] LDS -> 4-way min ->
//   fixed-order double tree-sum -> atomicExch partials[blk] + done-counter;
//   last block sums 512 partials (coherent atomic reads, fixed order).
// Math (proven R5-R13, absmax 0.0): d = |y|^2 - 2x.y + |x|^2 via
// v_mfma_f32_32x32x16_bf16, split-bf16, 13/16 K-slots; C/D layout m74/m101:
// col=lane&31, row=(reg&3)+8*(reg>>2)+4*half => in-lane min3 tree -> scalar.

#define BATCH 4
#define NPTS 8192
#define TPB 512
#define GRID 512                           // 2 * BATCH * XBLKS
#define XBLKS 64                           // 8192 / 128 cols
#define COLS_PER_BLOCK 128
#define ROWS_PER_GROUP 2048                // NPTS / 4 groups
#define JT 64                              // ROWS_PER_GROUP / 32

typedef __attribute__((ext_vector_type(8))) short bf16x8;
typedef __attribute__((ext_vector_type(16))) float f32x16;
union FragU { int4 i4; bf16x8 v; };

__device__ inline unsigned short bf16_rne(float f) {
    unsigned int u = __float_as_uint(f);
    return (unsigned short)((u + 0x7FFFu + ((u >> 16) & 1u)) >> 16);
}
__device__ inline float bf16_f32(unsigned short h) {
    return __uint_as_float(((unsigned int)h) << 16);
}
__device__ inline unsigned int pack2(unsigned int lo, unsigned int hi) {
    return (lo & 0xFFFFu) | (hi << 16);
}

// ---- prepack: frag both roles from raw xyz; zero the done-counter ----
__global__ __launch_bounds__(256) void prepack_kernel(
    const float* __restrict__ xyz1, const float* __restrict__ xyz2,
    int4* __restrict__ rowpack, int4* __restrict__ colpack,
    unsigned int* __restrict__ counter)
{
    const int id  = blockIdx.x * 256 + threadIdx.x;    // [0, 65536)
    const int arr = id >> 15;
    const int rem = id & 32767;                         // b*8192+n
    const float* p = (arr ? xyz2 : xyz1) + (size_t)rem * 3;
    const float x0 = p[0], x1 = p[1], x2 = p[2];

    if (id == 0) *counter = 0;

    const unsigned short h0 = bf16_rne(x0), h1 = bf16_rne(x1), h2 = bf16_rne(x2);
    const unsigned short l0 = bf16_rne(x0 - bf16_f32(h0));
    const unsigned short l1 = bf16_rne(x1 - bf16_f32(h1));
    const unsigned short l2 = bf16_rne(x2 - bf16_f32(h2));
    const float s = x0 * x0 + x1 * x1 + x2 * x2;
    const unsigned short sh = bf16_rne(s);
    const unsigned short sl = bf16_rne(s - bf16_f32(sh));
    const unsigned short one = 0x3F80;

    // row role: [h0,h1,h2,h0,h1,h2,l0,l1 | l2,one,one,sh,sl,0,0,0]
    int4 rlo, rhi;
    rlo.x = pack2(h0, h1); rlo.y = pack2(h2, h0);
    rlo.z = pack2(h1, h2); rlo.w = pack2(l0, l1);
    rhi.x = pack2(l2, one); rhi.y = pack2(one, sh);
    rhi.z = pack2(sl, 0u);  rhi.w = 0;
    rowpack[2 * id]     = rlo;
    rowpack[2 * id + 1] = rhi;

    // col role: g=-2x: [gh0,gh1,gh2,gl0,gl1,gl2,gh0,gh1 | gh2,sh,sl,one,one,0,0,0]
    const float g0 = -2.0f * x0, g1 = -2.0f * x1, g2 = -2.0f * x2;
    const unsigned short gh0 = bf16_rne(g0), gh1 = bf16_rne(g1), gh2 = bf16_rne(g2);
    const unsigned short gl0 = bf16_rne(g0 - bf16_f32(gh0));
    const unsigned short gl1 = bf16_rne(g1 - bf16_f32(gh1));
    const unsigned short gl2 = bf16_rne(g2 - bf16_f32(gh2));
    int4 clo, chi;
    clo.x = pack2(gh0, gh1); clo.y = pack2(gh2, gl0);
    clo.z = pack2(gl1, gl2); clo.w = pack2(gh0, gh1);
    chi.x = pack2(gh2, sh);  chi.y = pack2(sl, one);
    chi.z = pack2(one, 0u);  chi.w = 0;
    colpack[2 * id]     = clo;
    colpack[2 * id + 1] = chi;
}

__device__ inline float red16(float cb, const f32x16& d) {
    const float m0 = fminf(fminf(d[0],  d[1]),  d[2]);
    const float m1 = fminf(fminf(d[3],  d[4]),  d[5]);
    const float m2 = fminf(fminf(d[6],  d[7]),  d[8]);
    const float m3 = fminf(fminf(d[9],  d[10]), d[11]);
    const float m4 = fminf(fminf(d[12], d[13]), d[14]);
    const float u0 = fminf(fminf(m0, m1), m2);
    const float u1 = fminf(fminf(m3, m4), d[15]);
    return fminf(fminf(cb, u0), u1);
}

__global__ __launch_bounds__(TPB) void chamfer_main(
    const int4* __restrict__ rowpack,
    const int4* __restrict__ colpack,
    unsigned long long* __restrict__ partials,   // [GRID]
    unsigned int* __restrict__ counter,
    float* __restrict__ out)
{
    const int blk  = blockIdx.x;
    const int xblk = blk & (XBLKS - 1);
    const int b    = (blk >> 6) & (BATCH - 1);
    const int dir  = blk >> 8;
    const int arrB = dir;        // cols = array whose dist we output
    const int arrA = dir ^ 1;    // rows = the other array, streamed

    const int t = threadIdx.x, lane = t & 63, w = t >> 6;
    const int g  = w >> 1;            // row-group 0..3 (2048 rows each)
    const int wl = w & 1;             // col-subrange 0..1 (64 cols each)
    const int half = lane >> 5, l31 = lane & 31;

    __shared__ float part[4][COLS_PER_BLOCK];
    __shared__ double red[2];
    __shared__ unsigned int lastflag;

    // fixed B fragments: 2 col-tiles of 32 (cols cbase, cbase+32)
    const int cbase = xblk * COLS_PER_BLOCK + wl * 64 + l31;
    const size_t cidx = ((size_t)(arrB * BATCH + b) * NPTS + cbase) * 2;
    FragU bf0, bf1;
    bf0.i4 = colpack[cidx + half];
    bf1.i4 = colpack[cidx + 64 + half];       // +32 cols * 2 int4

    float cb0 = __builtin_inff();
    float cb1 = __builtin_inff();
    const f32x16 zero = {0.0f, 0.0f, 0.0f, 0.0f, 0.0f, 0.0f, 0.0f, 0.0f,
                         0.0f, 0.0f, 0.0f, 0.0f, 0.0f, 0.0f, 0.0f, 0.0f};

    // stream this group's 2048 rows directly from global (L2-served,
    // barrier-free; wave reads contiguous 2KB per jt)
    const int4* asrc = rowpack
        + ((size_t)(arrA * BATCH + b) * NPTS + (size_t)g * ROWS_PER_GROUP) * 2
        + (size_t)l31 * 2 + half;

#pragma unroll 4
    for (int jt = 0; jt < JT; ++jt) {
        FragU af; af.i4 = asrc[(size_t)jt * 64];
        f32x16 d0 = __builtin_amdgcn_mfma_f32_32x32x16_bf16(af.v, bf0.v, zero, 0, 0, 0);
        f32x16 d1 = __builtin_amdgcn_mfma_f32_32x32x16_bf16(af.v, bf1.v, zero, 0, 0, 0);
        cb0 = red16(cb0, d0);
        cb1 = red16(cb1, d1);
    }

    // ---- per-group col-mins -> LDS ----
    {
        const float v0 = fminf(cb0, __shfl_xor(cb0, 32, 64));
        const float v1 = fminf(cb1, __shfl_xor(cb1, 32, 64));
        if (half == 0) {
            part[g][wl * 64 + l31]      = v0;
            part[g][wl * 64 + 32 + l31] = v1;
        }
    }
    __syncthreads();

    // ---- combine 4 groups; fixed-order block sum (threads 0..127) ----
    double s = 0.0;
    if (t < COLS_PER_BLOCK) {
        const float m = fminf(fminf(part[0][t], part[1][t]),
                              fminf(part[2][t], part[3][t]));
        s = (double)m;
    }
    if (w < 2) {
        for (int off = 32; off > 0; off >>= 1) s += __shfl_down(s, off, 64);
        if (lane == 0) red[w] = s;
    }
    __syncthreads();
    if (t == 0) {
        const double bs = red[0] + red[1];
        atomicExch(&partials[blk], (unsigned long long)__double_as_longlong(bs));
        __threadfence();
        lastflag = (atomicAdd(counter, 1u) == GRID - 1) ? 1u : 0u;
    }
    __syncthreads();

    // ---- last block finalizes: fixed-order sum of 512 partials ----
    if (lastflag && w == 0) {
        double fs = 0.0;
#pragma unroll
        for (int i = 0; i < 8; ++i) {
            const unsigned long long pv =
                atomicAdd(&partials[lane * 8 + i], 0ull);   // coherent read
            fs += __longlong_as_double((long long)pv);
        }
        for (int off = 32; off > 0; off >>= 1) fs += __shfl_down(fs, off, 64);
        if (lane == 0)
            out[0] = (float)(fs / (double)(BATCH * NPTS));
    }
}

extern "C" void kernel_launch(void* const* d_in, const int* in_sizes, int n_in,
                              void* d_out, int out_size, void* d_ws, size_t ws_size,
                              hipStream_t stream) {
    const float* xyz1 = (const float*)d_in[0];
    const float* xyz2 = (const float*)d_in[1];
    float* out = (float*)d_out;

    int4* rowpack = (int4*)d_ws;                                  // 2 MB
    int4* colpack = rowpack + 2 * 65536;                          // 2 MB
    unsigned long long* partials = (unsigned long long*)(colpack + 2 * 65536);
    unsigned int* counter = (unsigned int*)(partials + GRID);

    prepack_kernel<<<256, 256, 0, stream>>>(xyz1, xyz2, rowpack, colpack, counter);

    chamfer_main<<<GRID, TPB, 0, stream>>>(rowpack, colpack, partials, counter, out);
}